// Round 12
// baseline (631.857 us; speedup 1.0000x reference)
//
#include <hip/hip_runtime.h>
#include <math.h>

#define N_NODES 50000
#define E_EDGES 800000
#define D 128
#define HID 128
#define NB 32
#define SCAN_BLOCKS 196   // ceil(50000/256)

typedef __attribute__((ext_vector_type(8))) short bf16x8;
typedef __attribute__((ext_vector_type(4))) float f32x4;

// packed-weight fragment-group bases (units of 64-lane fragment groups)
#define MW1F 0
#define MW2F 72
#define CW1F 104
#define NW1F 136
#define NW2F 200
#define TOT_KSTEPS 29

__device__ __forceinline__ short f2bf(float f) {
    union { float f; unsigned u; } v; v.f = f;
    unsigned r = v.u + 0x7fffu + ((v.u >> 16) & 1u);
    return (short)(r >> 16);
}
__device__ __forceinline__ float bf2f(unsigned s) {
    union { unsigned u; float f; } v; v.u = s << 16; return v.f;
}
// silu via hardware reciprocal (v_rcp_f32): ~1e-5 rel err, << bf16 rounding
__device__ __forceinline__ float silu_f(float x) {
    return x * __builtin_amdgcn_rcpf(1.0f + __expf(-x));
}
__device__ __forceinline__ f32x4 splat4(float b) { f32x4 v = {b, b, b, b}; return v; }

// ---------------------------------------------------------------------------
// Weight packing (one-time, cold)
// ---------------------------------------------------------------------------
__global__ void pack_w(const float* __restrict__ mw1, const float* __restrict__ mw2,
                       const float* __restrict__ cw1, const float* __restrict__ nw1,
                       const float* __restrict__ nw2, short* __restrict__ wp)
{
    const int bid = blockIdx.x;
    const int ks = bid >> 3, nf = bid & 7;
    const int l = threadIdx.x;
    const float* src; int k0;
    if (ks < 9)       { src = mw1; k0 = ks; }
    else if (ks < 13) { src = mw2; k0 = ks - 9; }
    else if (ks < 17) { src = cw1; k0 = ks - 13; }
    else if (ks < 25) { src = nw1; k0 = ks - 17; }
    else              { src = nw2; k0 = ks - 25; }
    bf16x8 pv;
    #pragma unroll
    for (int j = 0; j < 8; ++j)
        pv[j] = f2bf(src[(size_t)(k0 * 32 + (l >> 4) * 8 + j) * 128 + nf * 16 + (l & 15)]);
    *((bf16x8*)wp + (size_t)bid * 64 + l) = pv;
}

// conv_h fused with count_rows (identical grids: N*D/8 == E)
__global__ void prep(const float* __restrict__ h, const int* __restrict__ ei,
                     short* __restrict__ hb, int* __restrict__ cnt)
{
    int i = blockIdx.x * 256 + threadIdx.x;
    if (i < N_NODES * D / 8) {
        float4 va = ((const float4*)h)[i * 2];
        float4 vb = ((const float4*)h)[i * 2 + 1];
        bf16x8 o;
        o[0] = f2bf(va.x); o[1] = f2bf(va.y); o[2] = f2bf(va.z); o[3] = f2bf(va.w);
        o[4] = f2bf(vb.x); o[5] = f2bf(vb.y); o[6] = f2bf(vb.z); o[7] = f2bf(vb.w);
        ((bf16x8*)hb)[i] = o;
    }
    if (i < E_EDGES) atomicAdd(&cnt[ei[i]], 1);
}

// ---------------------------------------------------------------------------
// Counting sort of edges by row: count -> scan -> scatter perm
// ---------------------------------------------------------------------------
__global__ void scan_blocks(const int* __restrict__ cnt, int* __restrict__ base,
                            int* __restrict__ bsum)
{
    __shared__ int wsum[4];
    const int t = threadIdx.x, b = blockIdx.x;
    const int i = b * 256 + t;
    int v = (i < N_NODES) ? cnt[i] : 0;
    int incl = v;
    #pragma unroll
    for (int off = 1; off < 64; off <<= 1) {
        int u = __shfl_up(incl, off);
        if ((t & 63) >= off) incl += u;
    }
    if ((t & 63) == 63) wsum[t >> 6] = incl;
    __syncthreads();
    int wo = 0;
    #pragma unroll
    for (int wv = 0; wv < 4; ++wv) if (wv < (t >> 6)) wo += wsum[wv];
    if (i < N_NODES) base[i] = wo + incl - v;
    if (t == 255) bsum[b] = wo + incl;
}

__global__ void scan_bsums(const int* __restrict__ bsum, int* __restrict__ boff)
{
    __shared__ int wsum[4];
    const int t = threadIdx.x;
    int v = (t < SCAN_BLOCKS) ? bsum[t] : 0;
    int incl = v;
    #pragma unroll
    for (int off = 1; off < 64; off <<= 1) {
        int u = __shfl_up(incl, off);
        if ((t & 63) >= off) incl += u;
    }
    if ((t & 63) == 63) wsum[t >> 6] = incl;
    __syncthreads();
    int wo = 0;
    #pragma unroll
    for (int wv = 0; wv < 4; ++wv) if (wv < (t >> 6)) wo += wsum[wv];
    if (t < SCAN_BLOCKS) boff[t] = wo + incl - v;
}

__global__ void add_offsets(int* __restrict__ base, const int* __restrict__ boff,
                            int* __restrict__ fill)
{
    int i = blockIdx.x * 256 + threadIdx.x;
    if (i < N_NODES) {
        int v = base[i] + boff[blockIdx.x];
        base[i] = v; fill[i] = v;
    }
}

__global__ void scatter_edges(const int* __restrict__ ei, int* __restrict__ fill,
                              int* __restrict__ perm)
{
    int e = blockIdx.x * 256 + threadIdx.x;
    if (e < E_EDGES) {
        int p = atomicAdd(&fill[ei[e]], 1);
        perm[p] = e;
    }
}

// GEMM inner: 2 M-frags x 8 N-frags, A from swizzled LDS, B packed global.
#define GEMM2(KSTEPS, STRIDE, WBASE)                                           \
    _Pragma("unroll")                                                          \
    for (int ks = 0; ks < KSTEPS; ++ks) {                                      \
        const int kd = ks * 32 + ag * 8;                                       \
        int b0 = ar * STRIDE + kd * 2;        b0 ^= (ar & 7) << 4;             \
        int b1 = (16 + ar) * STRIDE + kd * 2; b1 ^= (ar & 7) << 4;             \
        bf16x8 a0 = *(const bf16x8*)(sx + b0);                                 \
        bf16x8 a1 = *(const bf16x8*)(sx + b1);                                 \
        const bf16x8* bw = wpv + (size_t)(WBASE + ks * 8) * 64 + l;            \
        _Pragma("unroll")                                                      \
        for (int n = 0; n < 8; ++n) {                                          \
            bf16x8 bb = bw[n * 64];                                            \
            acc0[n] = __builtin_amdgcn_mfma_f32_16x16x32_bf16(a0, bb, acc0[n], 0, 0, 0); \
            acc1[n] = __builtin_amdgcn_mfma_f32_16x16x32_bf16(a1, bb, acc1[n], 0, 0, 0); \
        }                                                                      \
    }

// ---------------------------------------------------------------------------
// Edge kernel: 128 threads = 2 waves, 32 SORTED edges per wave.
// __launch_bounds__(128,4): 64 arch VGPR + 64 acc = 128 total -> 4 waves/SIMD.
// L1 phase order: col loads ISSUED FIRST (random-access HBM misses), consumed
// LAST — gauss (reg-only) then rows (L2-hit sorted runs) provide ~700 cyc of
// latency cover. B-fragment index remapped accordingly (sum is order-invariant).
// ---------------------------------------------------------------------------
template<int GATHER>
__global__ __launch_bounds__(128, 4) void egnn_edge(
    const short* __restrict__ hb, const float* __restrict__ pos,
    const int* __restrict__ ei, const int* __restrict__ perm,
    const float* __restrict__ mb1, const float* __restrict__ mb2,
    const float* __restrict__ cb1, const float* __restrict__ cw2,
    const float* __restrict__ cb2, const short* __restrict__ wp,
    float* __restrict__ aggr_msgs, float* __restrict__ aggr_coord,
    short* __restrict__ msgb, float* __restrict__ cu)
{
    __shared__ char  sm[2][8192];          // per-wave H1/MSG [32][128] bf16, swizzled
    __shared__ int   s_row[2][32], s_col[2][32];
    __shared__ float s_dist[2][32];
    __shared__ float s_rel[2][32][3];

    const int t = threadIdx.x;
    const int w = t >> 6;
    const int l = t & 63;
    char* sx = sm[w];
    const bf16x8* wpv = (const bf16x8*)wp;
    const bf16x8* hbv = (const bf16x8*)hb;
    const int e0 = blockIdx.x * 64 + w * 32;

    if (l < 32) {
        const int ge = perm[e0 + l];
        const int row = ei[ge], col = ei[E_EDGES + ge];
        const float dx = pos[row * 3 + 0] - pos[col * 3 + 0];
        const float dy = pos[row * 3 + 1] - pos[col * 3 + 1];
        const float dz = pos[row * 3 + 2] - pos[col * 3 + 2];
        const float dist = sqrtf(dx * dx + dy * dy + dz * dz + 1e-8f);
        s_row[w][l] = row; s_col[w][l] = col; s_dist[w][l] = dist;
        s_rel[w][l][0] = dx; s_rel[w][l][1] = dy; s_rel[w][l][2] = dz;
    }
    asm volatile("s_waitcnt lgkmcnt(0)" ::: "memory");

    const int ar = l & 15, ag = l >> 4;
    const int row0 = s_row[w][ar],      col0 = s_col[w][ar];
    const int row1 = s_row[w][16 + ar], col1 = s_col[w][16 + ar];
    const float d0 = s_dist[w][ar], d1 = s_dist[w][16 + ar];

    const float GS = 10.0f / 31.0f;
    const float GC = -0.5f / (GS * GS);

    f32x4 acc0[8], acc1[8];

    // ---- L1: issue col gathers (HBM misses) up front ----
    bf16x8 c0[4], c1[4];
    #pragma unroll
    for (int j = 0; j < 4; ++j) {
        c0[j] = hbv[(size_t)col0 * 16 + j * 4 + ag];
        c1[j] = hbv[(size_t)col1 * 16 + j * 4 + ag];
    }

    #pragma unroll
    for (int n = 0; n < 8; ++n) {
        float b = mb1[n * 16 + ar];
        acc0[n] = splat4(b); acc1[n] = splat4(b);
    }

    // phase 0: gauss (reg-only); phases 1..4: rows (cache hits); 5..8: cols
    #pragma unroll
    for (int ph = 0; ph < 9; ++ph) {
        const int kidx = (ph == 0) ? 8 : (ph - 1);   // B K-slice for this phase
        bf16x8 a0, a1;
        if (ph == 0) {
            #pragma unroll
            for (int j = 0; j < 8; ++j) {
                const float g = (float)(ag * 8 + j) * GS;
                const float dd0 = d0 - g, dd1 = d1 - g;
                a0[j] = f2bf(__expf(GC * dd0 * dd0));
                a1[j] = f2bf(__expf(GC * dd1 * dd1));
            }
        } else if (ph < 5) {
            a0 = hbv[(size_t)row0 * 16 + (ph - 1) * 4 + ag];
            a1 = hbv[(size_t)row1 * 16 + (ph - 1) * 4 + ag];
        } else {
            a0 = c0[ph - 5];
            a1 = c1[ph - 5];
        }
        const bf16x8* bw = wpv + (size_t)(MW1F + kidx * 8) * 64 + l;
        #pragma unroll
        for (int n = 0; n < 8; ++n) {
            bf16x8 bb = bw[n * 64];
            acc0[n] = __builtin_amdgcn_mfma_f32_16x16x32_bf16(a0, bb, acc0[n], 0, 0, 0);
            acc1[n] = __builtin_amdgcn_mfma_f32_16x16x32_bf16(a1, bb, acc1[n], 0, 0, 0);
        }
    }

    #pragma unroll
    for (int m = 0; m < 2; ++m)
        #pragma unroll
        for (int n = 0; n < 8; ++n)
            #pragma unroll
            for (int r = 0; r < 4; ++r) {
                float x = (m == 0) ? acc0[n][r] : acc1[n][r];
                const int rw = m * 16 + ag * 4 + r;
                const int cl = n * 16 + ar;
                int byte = rw * 256 + cl * 2;
                byte ^= (rw & 7) << 4;
                *(short*)(sx + byte) = f2bf(silu_f(x));
            }
    asm volatile("s_waitcnt lgkmcnt(0)" ::: "memory");

    // ---- L2: H1 @ mw2 -> MSG ----
    #pragma unroll
    for (int n = 0; n < 8; ++n) {
        float b = mb2[n * 16 + ar];
        acc0[n] = splat4(b); acc1[n] = splat4(b);
    }
    GEMM2(4, 256, MW2F)

    int grows[2][4];
    #pragma unroll
    for (int m = 0; m < 2; ++m)
        #pragma unroll
        for (int r = 0; r < 4; ++r)
            grows[m][r] = s_row[w][m * 16 + ag * 4 + r];

    // store MSG bf16 to LDS (C1 input)
    #pragma unroll
    for (int m = 0; m < 2; ++m)
        #pragma unroll
        for (int n = 0; n < 8; ++n)
            #pragma unroll
            for (int r = 0; r < 4; ++r) {
                float x = (m == 0) ? acc0[n][r] : acc1[n][r];
                const int rw = m * 16 + ag * 4 + r;
                const int cl = n * 16 + ar;
                int byte = rw * 256 + cl * 2;
                byte ^= (rw & 7) << 4;
                *(short*)(sx + byte) = f2bf(x);
            }
    asm volatile("s_waitcnt lgkmcnt(0)" ::: "memory");

    if (GATHER) {
        // coalesced copy LDS MSG -> msgb (sorted order), non-temporal stream
        #pragma unroll
        for (int p = 0; p < 8; ++p) {
            const int rw = p * 4 + (l >> 4);
            int byte = rw * 256 + (l & 15) * 16;
            byte ^= (rw & 7) << 4;
            bf16x8 v = *(const bf16x8*)(sx + byte);
            __builtin_nontemporal_store(v,
                (bf16x8*)(msgb + (size_t)(e0 + rw) * D + (l & 15) * 8));
        }
    } else {
        // merged atomic scatter fallback
        #pragma unroll
        for (int m = 0; m < 2; ++m)
            #pragma unroll
            for (int n = 0; n < 8; ++n) {
                const int cl = n * 16 + ar;
                float s = (m == 0) ? acc0[n][0] : acc1[n][0];
                #pragma unroll
                for (int r = 0; r < 3; ++r) {
                    float nxt = (m == 0) ? acc0[n][r + 1] : acc1[n][r + 1];
                    if (grows[m][r + 1] == grows[m][r]) s += nxt;
                    else {
                        atomicAdd(&aggr_msgs[(size_t)grows[m][r] * D + cl], s);
                        s = nxt;
                    }
                }
                atomicAdd(&aggr_msgs[(size_t)grows[m][3] * D + cl], s);
            }
    }

    // ---- C1: MSG @ cw1 ----
    #pragma unroll
    for (int n = 0; n < 8; ++n) {
        float b = cb1[n * 16 + ar];
        acc0[n] = splat4(b); acc1[n] = splat4(b);
    }
    GEMM2(4, 256, CW1F)

    // ---- C2: per-edge scalar dot + coord output ----
    float cw2v[8];
    #pragma unroll
    for (int n = 0; n < 8; ++n) cw2v[n] = cw2[n * 16 + ar];
    float p0[4], p1[4];
    #pragma unroll
    for (int r = 0; r < 4; ++r) {
        float s0 = 0.f, s1 = 0.f;
        #pragma unroll
        for (int n = 0; n < 8; ++n) {
            s0 += silu_f(acc0[n][r]) * cw2v[n];
            s1 += silu_f(acc1[n][r]) * cw2v[n];
        }
        p0[r] = s0; p1[r] = s1;
    }
    #pragma unroll
    for (int off = 1; off < 16; off <<= 1) {
        #pragma unroll
        for (int r = 0; r < 4; ++r) {
            p0[r] += __shfl_xor(p0[r], off);
            p1[r] += __shfl_xor(p1[r], off);
        }
    }
    if (ar == 0) {
        const float cb = cb2[0];
        if (GATHER) {
            #pragma unroll
            for (int m = 0; m < 2; ++m)
                #pragma unroll
                for (int r = 0; r < 4; ++r) {
                    const int el = m * 16 + ag * 4 + r;
                    const int ge = e0 + el;
                    const float mm = ((m == 0) ? p0[r] : p1[r]) + cb;
                    float* dst = cu + (size_t)ge * 3;
                    __builtin_nontemporal_store(s_rel[w][el][0] * mm, dst + 0);
                    __builtin_nontemporal_store(s_rel[w][el][1] * mm, dst + 1);
                    __builtin_nontemporal_store(s_rel[w][el][2] * mm, dst + 2);
                }
        } else {
            #pragma unroll
            for (int m = 0; m < 2; ++m) {
                float cx = 0.f, cy = 0.f, cz = 0.f;
                int rprev = grows[m][0];
                #pragma unroll
                for (int r = 0; r < 4; ++r) {
                    const int el = m * 16 + ag * 4 + r;
                    const int gr = grows[m][r];
                    const float mm = ((m == 0) ? p0[r] : p1[r]) + cb;
                    if (gr != rprev) {
                        atomicAdd(&aggr_coord[rprev * 3 + 0], cx);
                        atomicAdd(&aggr_coord[rprev * 3 + 1], cy);
                        atomicAdd(&aggr_coord[rprev * 3 + 2], cz);
                        cx = 0.f; cy = 0.f; cz = 0.f; rprev = gr;
                    }
                    cx += s_rel[w][el][0] * mm;
                    cy += s_rel[w][el][1] * mm;
                    cz += s_rel[w][el][2] * mm;
                }
                atomicAdd(&aggr_coord[rprev * 3 + 0], cx);
                atomicAdd(&aggr_coord[rprev * 3 + 1], cy);
                atomicAdd(&aggr_coord[rprev * 3 + 2], cz);
            }
        }
    }
}

// ---------------------------------------------------------------------------
// Gather aggregation: one wave per node sums its contiguous message run.
// Writes bf16 (node kernel converted to bf16 anyway -> identical numerics).
// Messages are a read-once stream: non-temporal loads.
// ---------------------------------------------------------------------------
__global__ __launch_bounds__(256) void aggr_gather(
    const short* __restrict__ msgb, const int* __restrict__ base,
    const int* __restrict__ fill, short* __restrict__ aggrb)
{
    const int node = blockIdx.x * 4 + (threadIdx.x >> 6);
    if (node >= N_NODES) return;
    const int l = threadIdx.x & 63;
    const int b = base[node], e = fill[node];
    const unsigned* mv = (const unsigned*)msgb;
    float a0 = 0.f, a1 = 0.f;
    for (int i = b; i < e; ++i) {
        unsigned v = __builtin_nontemporal_load(mv + (size_t)i * 64 + l);
        a0 += bf2f(v & 0xffffu);
        a1 += bf2f(v >> 16);
    }
    unsigned u = ((unsigned)(unsigned short)f2bf(a1) << 16) |
                 (unsigned)(unsigned short)f2bf(a0);
    ((unsigned*)aggrb)[(size_t)node * 64 + l] = u;
}

// separate coord_pos (r6-validated; fusing into aggr_gather was the r10 regression)
__global__ void coord_pos(const float* __restrict__ pos, const float* __restrict__ cu,
                          const int* __restrict__ base, const int* __restrict__ fill,
                          float* __restrict__ pout)
{
    int n = blockIdx.x * 256 + threadIdx.x;
    if (n < N_NODES) {
        const int b = base[n], e = fill[n];
        float ax = 0.f, ay = 0.f, az = 0.f;
        for (int i = b; i < e; ++i) {
            ax += cu[(size_t)i * 3 + 0];
            ay += cu[(size_t)i * 3 + 1];
            az += cu[(size_t)i * 3 + 2];
        }
        pout[n * 3 + 0] = pos[n * 3 + 0] + ax;
        pout[n * 3 + 1] = pos[n * 3 + 1] + ay;
        pout[n * 3 + 2] = pos[n * 3 + 2] + az;
    }
}

// ---------------------------------------------------------------------------
// Node kernel: h_out = h + mlp([h, aggr]); 2 waves x 32 nodes.
// GATHER=1: stages X directly from bf16 hb + aggrb (no conversion VALU).
// GATHER=0: r6 fp32 staging from h + aggr_msgs (fallback).
// ---------------------------------------------------------------------------
template<int GATHER>
__global__ __launch_bounds__(128, 2) void egnn_node(
    const float* __restrict__ h, const float* __restrict__ aggrf,
    const short* __restrict__ hb, const short* __restrict__ aggrb,
    const float* __restrict__ nb1, const float* __restrict__ nb2,
    const short* __restrict__ wp, float* __restrict__ out)
{
    __shared__ char sm[2][16384];
    const int t = threadIdx.x, w = t >> 6, l = t & 63;
    char* sx = sm[w];
    const bf16x8* wpv = (const bf16x8*)wp;
    const int n0 = blockIdx.x * 64 + w * 32;

    {
        const int n_loc = l & 31, half = l >> 5;
        int gn = n0 + n_loc; if (gn >= N_NODES) gn = N_NODES - 1;
        if (GATHER) {
            const bf16x8* src = (half == 0)
                ? ((const bf16x8*)hb    + (size_t)gn * 16)
                : ((const bf16x8*)aggrb + (size_t)gn * 16);
            #pragma unroll
            for (int c = 0; c < 16; ++c) {
                bf16x8 sv = src[c];
                int byte = n_loc * 512 + (half * 128 + c * 8) * 2;
                byte ^= (n_loc & 7) << 4;
                *(bf16x8*)(sx + byte) = sv;
            }
        } else {
            const float* src = (half == 0) ? (h + (size_t)gn * D)
                                           : (aggrf + (size_t)gn * D);
            #pragma unroll
            for (int c = 0; c < 16; ++c) {
                float4 va = *(const float4*)(src + c * 8);
                float4 vb = *(const float4*)(src + c * 8 + 4);
                float v[8] = {va.x, va.y, va.z, va.w, vb.x, vb.y, vb.z, vb.w};
                bf16x8 sv;
                #pragma unroll
                for (int j = 0; j < 8; ++j) sv[j] = f2bf(v[j]);
                int byte = n_loc * 512 + (half * 128 + c * 8) * 2;
                byte ^= (n_loc & 7) << 4;
                *(bf16x8*)(sx + byte) = sv;
            }
        }
    }
    asm volatile("s_waitcnt lgkmcnt(0)" ::: "memory");

    const int ar = l & 15, ag = l >> 4;
    f32x4 acc0[8], acc1[8];

    #pragma unroll
    for (int n = 0; n < 8; ++n) {
        float b = nb1[n * 16 + ar];
        acc0[n] = splat4(b); acc1[n] = splat4(b);
    }
    GEMM2(8, 512, NW1F)

    #pragma unroll
    for (int m = 0; m < 2; ++m)
        #pragma unroll
        for (int n = 0; n < 8; ++n)
            #pragma unroll
            for (int r = 0; r < 4; ++r) {
                float x = (m == 0) ? acc0[n][r] : acc1[n][r];
                const int rw = m * 16 + ag * 4 + r;
                const int cl = n * 16 + ar;
                int byte = rw * 256 + cl * 2;
                byte ^= (rw & 7) << 4;
                *(short*)(sx + byte) = f2bf(silu_f(x));
            }
    asm volatile("s_waitcnt lgkmcnt(0)" ::: "memory");

    #pragma unroll
    for (int n = 0; n < 8; ++n) {
        float b = nb2[n * 16 + ar];
        acc0[n] = splat4(b); acc1[n] = splat4(b);
    }
    GEMM2(4, 256, NW2F)

    #pragma unroll
    for (int m = 0; m < 2; ++m)
        #pragma unroll
        for (int n = 0; n < 8; ++n)
            #pragma unroll
            for (int r = 0; r < 4; ++r) {
                const int rw = m * 16 + ag * 4 + r;
                const int gnode = n0 + rw;
                if (gnode < N_NODES) {
                    const int cl = n * 16 + ar;
                    float x = (m == 0) ? acc0[n][r] : acc1[n][r];
                    out[(size_t)gnode * D + cl] = h[(size_t)gnode * D + cl] + x;
                }
            }
}

__global__ void egnn_pos(const float* __restrict__ pos,
                         const float* __restrict__ aggr_coord,
                         float* __restrict__ pout)
{
    int i = blockIdx.x * 256 + threadIdx.x;
    if (i < N_NODES * 3) pout[i] = pos[i] + aggr_coord[i];
}

extern "C" void kernel_launch(void* const* d_in, const int* in_sizes, int n_in,
                              void* d_out, int out_size, void* d_ws, size_t ws_size,
                              hipStream_t stream)
{
    const float* h   = (const float*)d_in[0];
    const float* pos = (const float*)d_in[1];
    const int*   ei  = (const int*)d_in[2];
    const float* mw1 = (const float*)d_in[3];
    const float* mb1 = (const float*)d_in[4];
    const float* mw2 = (const float*)d_in[5];
    const float* mb2 = (const float*)d_in[6];
    const float* nw1 = (const float*)d_in[7];
    const float* nb1 = (const float*)d_in[8];
    const float* nw2 = (const float*)d_in[9];
    const float* nb2 = (const float*)d_in[10];
    const float* cw1 = (const float*)d_in[11];
    const float* cb1 = (const float*)d_in[12];
    const float* cw2 = (const float*)d_in[13];
    const float* cb2 = (const float*)d_in[14];

    float* out = (float*)d_out;
    char*  ws  = (char*)d_ws;

    size_t o = 0;
    #define WALLOC(name, bytes) size_t name = o; o = (o + (size_t)(bytes) + 15) & ~(size_t)15;
    WALLOC(o_aggrm, (size_t)N_NODES * D * 4)      // fp32 aggr (fallback) / bf16 aggrb (gather)
    WALLOC(o_aggrc, (size_t)N_NODES * 3 * 4)
    WALLOC(o_wpack, (size_t)TOT_KSTEPS * 8 * 64 * 8 * 2)
    WALLOC(o_hb,    (size_t)N_NODES * D * 2)
    WALLOC(o_cnt,   (size_t)N_NODES * 4)
    WALLOC(o_base,  (size_t)N_NODES * 4)
    WALLOC(o_fill,  (size_t)N_NODES * 4)
    WALLOC(o_bsum,  256 * 4)
    WALLOC(o_boff,  256 * 4)
    WALLOC(o_perm,  (size_t)E_EDGES * 4)
    WALLOC(o_msgb,  (size_t)E_EDGES * D * 2)
    WALLOC(o_cu,    (size_t)E_EDGES * 3 * 4)
    const size_t needed = o;
    #undef WALLOC

    float* aggr_msgs  = (float*)(ws + o_aggrm);
    short* aggrb      = (short*)(ws + o_aggrm);   // bf16 alias (paths disjoint)
    float* aggr_coord = (float*)(ws + o_aggrc);
    short* wpack      = (short*)(ws + o_wpack);
    short* hb         = (short*)(ws + o_hb);
    int*   cnt        = (int*)(ws + o_cnt);
    int*   base       = (int*)(ws + o_base);
    int*   fill       = (int*)(ws + o_fill);
    int*   bsum       = (int*)(ws + o_bsum);
    int*   boff       = (int*)(ws + o_boff);
    int*   perm       = (int*)(ws + o_perm);
    short* msgb       = (short*)(ws + o_msgb);
    float* cu         = (float*)(ws + o_cu);

    const bool gather = (ws_size >= needed);

    hipMemsetAsync(cnt, 0, (size_t)N_NODES * sizeof(int), stream);
    if (!gather)
        hipMemsetAsync(aggr_msgs, 0,
                       (size_t)(N_NODES * D + N_NODES * 3) * sizeof(float), stream);

    pack_w<<<TOT_KSTEPS * 8, 64, 0, stream>>>(mw1, mw2, cw1, nw1, nw2, wpack);
    prep<<<(E_EDGES + 255) / 256, 256, 0, stream>>>(h, ei, hb, cnt);

    scan_blocks<<<SCAN_BLOCKS, 256, 0, stream>>>(cnt, base, bsum);
    scan_bsums<<<1, 256, 0, stream>>>(bsum, boff);
    add_offsets<<<SCAN_BLOCKS, 256, 0, stream>>>(base, boff, fill);
    scatter_edges<<<(E_EDGES + 255) / 256, 256, 0, stream>>>(ei, fill, perm);

    if (gather) {
        egnn_edge<1><<<E_EDGES / 64, 128, 0, stream>>>(
            hb, pos, ei, perm, mb1, mb2, cb1, cw2, cb2, wpack,
            aggr_msgs, aggr_coord, msgb, cu);
        aggr_gather<<<(N_NODES + 3) / 4, 256, 0, stream>>>(msgb, base, fill, aggrb);
        egnn_node<1><<<(N_NODES + 63) / 64, 128, 0, stream>>>(
            h, aggr_msgs, hb, aggrb, nb1, nb2, wpack, out);
        coord_pos<<<(N_NODES + 255) / 256, 256, 0, stream>>>(
            pos, cu, base, fill, out + (size_t)N_NODES * D);
    } else {
        egnn_edge<0><<<E_EDGES / 64, 128, 0, stream>>>(
            hb, pos, ei, perm, mb1, mb2, cb1, cw2, cb2, wpack,
            aggr_msgs, aggr_coord, msgb, cu);
        egnn_node<0><<<(N_NODES + 63) / 64, 128, 0, stream>>>(
            h, aggr_msgs, hb, aggrb, nb1, nb2, wpack, out);
        egnn_pos<<<(N_NODES * 3 + 255) / 256, 256, 0, stream>>>(
            pos, aggr_coord, out + (size_t)N_NODES * D);
    }
}

// Round 13
// 562.085 us; speedup vs baseline: 1.1241x; 1.1241x over previous
//
#include <hip/hip_runtime.h>
#include <math.h>

#define N_NODES 50000
#define E_EDGES 800000
#define D 128
#define HID 128
#define NB 32
#define SCAN_BLOCKS 196   // ceil(50000/256)

typedef __attribute__((ext_vector_type(8))) short bf16x8;
typedef __attribute__((ext_vector_type(4))) float f32x4;

// packed-weight fragment-group bases (units of 64-lane fragment groups)
#define MW1F 0
#define MW2F 72
#define CW1F 104
#define NW1F 136
#define NW2F 200
#define TOT_KSTEPS 29

__device__ __forceinline__ short f2bf(float f) {
    union { float f; unsigned u; } v; v.f = f;
    unsigned r = v.u + 0x7fffu + ((v.u >> 16) & 1u);
    return (short)(r >> 16);
}
__device__ __forceinline__ float bf2f(unsigned s) {
    union { unsigned u; float f; } v; v.u = s << 16; return v.f;
}
// silu via hardware reciprocal (v_rcp_f32): ~1e-5 rel err, << bf16 rounding
__device__ __forceinline__ float silu_f(float x) {
    return x * __builtin_amdgcn_rcpf(1.0f + __expf(-x));
}
__device__ __forceinline__ f32x4 splat4(float b) { f32x4 v = {b, b, b, b}; return v; }

// ---------------------------------------------------------------------------
// Weight packing (one-time, cold)
// ---------------------------------------------------------------------------
__global__ void pack_w(const float* __restrict__ mw1, const float* __restrict__ mw2,
                       const float* __restrict__ cw1, const float* __restrict__ nw1,
                       const float* __restrict__ nw2, short* __restrict__ wp)
{
    const int bid = blockIdx.x;
    const int ks = bid >> 3, nf = bid & 7;
    const int l = threadIdx.x;
    const float* src; int k0;
    if (ks < 9)       { src = mw1; k0 = ks; }
    else if (ks < 13) { src = mw2; k0 = ks - 9; }
    else if (ks < 17) { src = cw1; k0 = ks - 13; }
    else if (ks < 25) { src = nw1; k0 = ks - 17; }
    else              { src = nw2; k0 = ks - 25; }
    bf16x8 pv;
    #pragma unroll
    for (int j = 0; j < 8; ++j)
        pv[j] = f2bf(src[(size_t)(k0 * 32 + (l >> 4) * 8 + j) * 128 + nf * 16 + (l & 15)]);
    *((bf16x8*)wp + (size_t)bid * 64 + l) = pv;
}

// conv_h fused with count_rows (identical grids: N*D/8 == E)
__global__ void prep(const float* __restrict__ h, const int* __restrict__ ei,
                     short* __restrict__ hb, int* __restrict__ cnt)
{
    int i = blockIdx.x * 256 + threadIdx.x;
    if (i < N_NODES * D / 8) {
        float4 va = ((const float4*)h)[i * 2];
        float4 vb = ((const float4*)h)[i * 2 + 1];
        bf16x8 o;
        o[0] = f2bf(va.x); o[1] = f2bf(va.y); o[2] = f2bf(va.z); o[3] = f2bf(va.w);
        o[4] = f2bf(vb.x); o[5] = f2bf(vb.y); o[6] = f2bf(vb.z); o[7] = f2bf(vb.w);
        ((bf16x8*)hb)[i] = o;
    }
    if (i < E_EDGES) atomicAdd(&cnt[ei[i]], 1);
}

// ---------------------------------------------------------------------------
// Counting sort of edges by row: count -> scan -> scatter perm
// ---------------------------------------------------------------------------
__global__ void scan_blocks(const int* __restrict__ cnt, int* __restrict__ base,
                            int* __restrict__ bsum)
{
    __shared__ int wsum[4];
    const int t = threadIdx.x, b = blockIdx.x;
    const int i = b * 256 + t;
    int v = (i < N_NODES) ? cnt[i] : 0;
    int incl = v;
    #pragma unroll
    for (int off = 1; off < 64; off <<= 1) {
        int u = __shfl_up(incl, off);
        if ((t & 63) >= off) incl += u;
    }
    if ((t & 63) == 63) wsum[t >> 6] = incl;
    __syncthreads();
    int wo = 0;
    #pragma unroll
    for (int wv = 0; wv < 4; ++wv) if (wv < (t >> 6)) wo += wsum[wv];
    if (i < N_NODES) base[i] = wo + incl - v;
    if (t == 255) bsum[b] = wo + incl;
}

__global__ void scan_bsums(const int* __restrict__ bsum, int* __restrict__ boff)
{
    __shared__ int wsum[4];
    const int t = threadIdx.x;
    int v = (t < SCAN_BLOCKS) ? bsum[t] : 0;
    int incl = v;
    #pragma unroll
    for (int off = 1; off < 64; off <<= 1) {
        int u = __shfl_up(incl, off);
        if ((t & 63) >= off) incl += u;
    }
    if ((t & 63) == 63) wsum[t >> 6] = incl;
    __syncthreads();
    int wo = 0;
    #pragma unroll
    for (int wv = 0; wv < 4; ++wv) if (wv < (t >> 6)) wo += wsum[wv];
    if (t < SCAN_BLOCKS) boff[t] = wo + incl - v;
}

__global__ void add_offsets(int* __restrict__ base, const int* __restrict__ boff,
                            int* __restrict__ fill)
{
    int i = blockIdx.x * 256 + threadIdx.x;
    if (i < N_NODES) {
        int v = base[i] + boff[blockIdx.x];
        base[i] = v; fill[i] = v;
    }
}

__global__ void scatter_edges(const int* __restrict__ ei, int* __restrict__ fill,
                              int* __restrict__ perm)
{
    int e = blockIdx.x * 256 + threadIdx.x;
    if (e < E_EDGES) {
        int p = atomicAdd(&fill[ei[e]], 1);
        perm[p] = e;
    }
}

// GEMM inner: 2 M-frags x 8 N-frags, A from swizzled LDS, B packed global.
#define GEMM2(KSTEPS, STRIDE, WBASE)                                           \
    _Pragma("unroll")                                                          \
    for (int ks = 0; ks < KSTEPS; ++ks) {                                      \
        const int kd = ks * 32 + ag * 8;                                       \
        int b0 = ar * STRIDE + kd * 2;        b0 ^= (ar & 7) << 4;             \
        int b1 = (16 + ar) * STRIDE + kd * 2; b1 ^= (ar & 7) << 4;             \
        bf16x8 a0 = *(const bf16x8*)(sx + b0);                                 \
        bf16x8 a1 = *(const bf16x8*)(sx + b1);                                 \
        const bf16x8* bw = wpv + (size_t)(WBASE + ks * 8) * 64 + l;            \
        _Pragma("unroll")                                                      \
        for (int n = 0; n < 8; ++n) {                                          \
            bf16x8 bb = bw[n * 64];                                            \
            acc0[n] = __builtin_amdgcn_mfma_f32_16x16x32_bf16(a0, bb, acc0[n], 0, 0, 0); \
            acc1[n] = __builtin_amdgcn_mfma_f32_16x16x32_bf16(a1, bb, acc1[n], 0, 0, 0); \
        }                                                                      \
    }

// ---------------------------------------------------------------------------
// Edge kernel: 128 threads = 2 waves, 32 SORTED edges per wave.
// __launch_bounds__(128,4): 64 arch VGPR + 64 acc = 128 total -> 4 waves/SIMD.
// NOTE (r12 lesson): do NOT hoist col loads into registers — 64-reg cap turns
// extra in-flight fragments into scratch spills (FETCH/WRITE +90/+140 MB).
// Per-phase load placement (r11) is compiler-optimal within the budget.
// ---------------------------------------------------------------------------
template<int GATHER>
__global__ __launch_bounds__(128, 4) void egnn_edge(
    const short* __restrict__ hb, const float* __restrict__ pos,
    const int* __restrict__ ei, const int* __restrict__ perm,
    const float* __restrict__ mb1, const float* __restrict__ mb2,
    const float* __restrict__ cb1, const float* __restrict__ cw2,
    const float* __restrict__ cb2, const short* __restrict__ wp,
    float* __restrict__ aggr_msgs, float* __restrict__ aggr_coord,
    short* __restrict__ msgb, float* __restrict__ cu)
{
    __shared__ char  sm[2][8192];          // per-wave H1/MSG [32][128] bf16, swizzled
    __shared__ int   s_row[2][32], s_col[2][32];
    __shared__ float s_dist[2][32];
    __shared__ float s_rel[2][32][3];

    const int t = threadIdx.x;
    const int w = t >> 6;
    const int l = t & 63;
    char* sx = sm[w];
    const bf16x8* wpv = (const bf16x8*)wp;
    const bf16x8* hbv = (const bf16x8*)hb;
    const int e0 = blockIdx.x * 64 + w * 32;

    if (l < 32) {
        const int ge = perm[e0 + l];
        const int row = ei[ge], col = ei[E_EDGES + ge];
        const float dx = pos[row * 3 + 0] - pos[col * 3 + 0];
        const float dy = pos[row * 3 + 1] - pos[col * 3 + 1];
        const float dz = pos[row * 3 + 2] - pos[col * 3 + 2];
        const float dist = sqrtf(dx * dx + dy * dy + dz * dz + 1e-8f);
        s_row[w][l] = row; s_col[w][l] = col; s_dist[w][l] = dist;
        s_rel[w][l][0] = dx; s_rel[w][l][1] = dy; s_rel[w][l][2] = dz;
    }
    asm volatile("s_waitcnt lgkmcnt(0)" ::: "memory");

    const int ar = l & 15, ag = l >> 4;
    const int row0 = s_row[w][ar],      col0 = s_col[w][ar];
    const int row1 = s_row[w][16 + ar], col1 = s_col[w][16 + ar];
    const float d0 = s_dist[w][ar], d1 = s_dist[w][16 + ar];

    const float GS = 10.0f / 31.0f;
    const float GC = -0.5f / (GS * GS);

    f32x4 acc0[8], acc1[8];

    // ---- L1: A direct from global bf16 h + in-register gauss ----
    #pragma unroll
    for (int n = 0; n < 8; ++n) {
        float b = mb1[n * 16 + ar];
        acc0[n] = splat4(b); acc1[n] = splat4(b);
    }
    #pragma unroll
    for (int ks = 0; ks < 9; ++ks) {
        bf16x8 a0, a1;
        if (ks < 4) {
            a0 = hbv[(size_t)row0 * 16 + ks * 4 + ag];
            a1 = hbv[(size_t)row1 * 16 + ks * 4 + ag];
        } else if (ks < 8) {
            a0 = hbv[(size_t)col0 * 16 + (ks - 4) * 4 + ag];
            a1 = hbv[(size_t)col1 * 16 + (ks - 4) * 4 + ag];
        } else {
            #pragma unroll
            for (int j = 0; j < 8; ++j) {
                const float g = (float)(ag * 8 + j) * GS;
                const float dd0 = d0 - g, dd1 = d1 - g;
                a0[j] = f2bf(__expf(GC * dd0 * dd0));
                a1[j] = f2bf(__expf(GC * dd1 * dd1));
            }
        }
        const bf16x8* bw = wpv + (size_t)(MW1F + ks * 8) * 64 + l;
        #pragma unroll
        for (int n = 0; n < 8; ++n) {
            bf16x8 bb = bw[n * 64];
            acc0[n] = __builtin_amdgcn_mfma_f32_16x16x32_bf16(a0, bb, acc0[n], 0, 0, 0);
            acc1[n] = __builtin_amdgcn_mfma_f32_16x16x32_bf16(a1, bb, acc1[n], 0, 0, 0);
        }
    }

    #pragma unroll
    for (int m = 0; m < 2; ++m)
        #pragma unroll
        for (int n = 0; n < 8; ++n)
            #pragma unroll
            for (int r = 0; r < 4; ++r) {
                float x = (m == 0) ? acc0[n][r] : acc1[n][r];
                const int rw = m * 16 + ag * 4 + r;
                const int cl = n * 16 + ar;
                int byte = rw * 256 + cl * 2;
                byte ^= (rw & 7) << 4;
                *(short*)(sx + byte) = f2bf(silu_f(x));
            }
    asm volatile("s_waitcnt lgkmcnt(0)" ::: "memory");

    // ---- L2: H1 @ mw2 -> MSG ----
    #pragma unroll
    for (int n = 0; n < 8; ++n) {
        float b = mb2[n * 16 + ar];
        acc0[n] = splat4(b); acc1[n] = splat4(b);
    }
    GEMM2(4, 256, MW2F)

    int grows[2][4];
    #pragma unroll
    for (int m = 0; m < 2; ++m)
        #pragma unroll
        for (int r = 0; r < 4; ++r)
            grows[m][r] = s_row[w][m * 16 + ag * 4 + r];

    // store MSG bf16 to LDS (C1 input)
    #pragma unroll
    for (int m = 0; m < 2; ++m)
        #pragma unroll
        for (int n = 0; n < 8; ++n)
            #pragma unroll
            for (int r = 0; r < 4; ++r) {
                float x = (m == 0) ? acc0[n][r] : acc1[n][r];
                const int rw = m * 16 + ag * 4 + r;
                const int cl = n * 16 + ar;
                int byte = rw * 256 + cl * 2;
                byte ^= (rw & 7) << 4;
                *(short*)(sx + byte) = f2bf(x);
            }
    asm volatile("s_waitcnt lgkmcnt(0)" ::: "memory");

    if (GATHER) {
        // coalesced copy LDS MSG -> msgb (sorted order), non-temporal stream
        #pragma unroll
        for (int p = 0; p < 8; ++p) {
            const int rw = p * 4 + (l >> 4);
            int byte = rw * 256 + (l & 15) * 16;
            byte ^= (rw & 7) << 4;
            bf16x8 v = *(const bf16x8*)(sx + byte);
            __builtin_nontemporal_store(v,
                (bf16x8*)(msgb + (size_t)(e0 + rw) * D + (l & 15) * 8));
        }
    } else {
        // merged atomic scatter fallback
        #pragma unroll
        for (int m = 0; m < 2; ++m)
            #pragma unroll
            for (int n = 0; n < 8; ++n) {
                const int cl = n * 16 + ar;
                float s = (m == 0) ? acc0[n][0] : acc1[n][0];
                #pragma unroll
                for (int r = 0; r < 3; ++r) {
                    float nxt = (m == 0) ? acc0[n][r + 1] : acc1[n][r + 1];
                    if (grows[m][r + 1] == grows[m][r]) s += nxt;
                    else {
                        atomicAdd(&aggr_msgs[(size_t)grows[m][r] * D + cl], s);
                        s = nxt;
                    }
                }
                atomicAdd(&aggr_msgs[(size_t)grows[m][3] * D + cl], s);
            }
    }

    // ---- C1: MSG @ cw1 ----
    #pragma unroll
    for (int n = 0; n < 8; ++n) {
        float b = cb1[n * 16 + ar];
        acc0[n] = splat4(b); acc1[n] = splat4(b);
    }
    GEMM2(4, 256, CW1F)

    // ---- C2: per-edge scalar dot + coord output ----
    float cw2v[8];
    #pragma unroll
    for (int n = 0; n < 8; ++n) cw2v[n] = cw2[n * 16 + ar];
    float p0[4], p1[4];
    #pragma unroll
    for (int r = 0; r < 4; ++r) {
        float s0 = 0.f, s1 = 0.f;
        #pragma unroll
        for (int n = 0; n < 8; ++n) {
            s0 += silu_f(acc0[n][r]) * cw2v[n];
            s1 += silu_f(acc1[n][r]) * cw2v[n];
        }
        p0[r] = s0; p1[r] = s1;
    }
    #pragma unroll
    for (int off = 1; off < 16; off <<= 1) {
        #pragma unroll
        for (int r = 0; r < 4; ++r) {
            p0[r] += __shfl_xor(p0[r], off);
            p1[r] += __shfl_xor(p1[r], off);
        }
    }
    if (ar == 0) {
        const float cb = cb2[0];
        if (GATHER) {
            #pragma unroll
            for (int m = 0; m < 2; ++m)
                #pragma unroll
                for (int r = 0; r < 4; ++r) {
                    const int el = m * 16 + ag * 4 + r;
                    const int ge = e0 + el;
                    const float mm = ((m == 0) ? p0[r] : p1[r]) + cb;
                    float* dst = cu + (size_t)ge * 3;
                    __builtin_nontemporal_store(s_rel[w][el][0] * mm, dst + 0);
                    __builtin_nontemporal_store(s_rel[w][el][1] * mm, dst + 1);
                    __builtin_nontemporal_store(s_rel[w][el][2] * mm, dst + 2);
                }
        } else {
            #pragma unroll
            for (int m = 0; m < 2; ++m) {
                float cx = 0.f, cy = 0.f, cz = 0.f;
                int rprev = grows[m][0];
                #pragma unroll
                for (int r = 0; r < 4; ++r) {
                    const int el = m * 16 + ag * 4 + r;
                    const int gr = grows[m][r];
                    const float mm = ((m == 0) ? p0[r] : p1[r]) + cb;
                    if (gr != rprev) {
                        atomicAdd(&aggr_coord[rprev * 3 + 0], cx);
                        atomicAdd(&aggr_coord[rprev * 3 + 1], cy);
                        atomicAdd(&aggr_coord[rprev * 3 + 2], cz);
                        cx = 0.f; cy = 0.f; cz = 0.f; rprev = gr;
                    }
                    cx += s_rel[w][el][0] * mm;
                    cy += s_rel[w][el][1] * mm;
                    cz += s_rel[w][el][2] * mm;
                }
                atomicAdd(&aggr_coord[rprev * 3 + 0], cx);
                atomicAdd(&aggr_coord[rprev * 3 + 1], cy);
                atomicAdd(&aggr_coord[rprev * 3 + 2], cz);
            }
        }
    }
}

// ---------------------------------------------------------------------------
// Gather aggregation: one wave per node sums its contiguous message run.
// Dual-accumulator unroll-2: avg run = 16 iterations of 256B loads; two
// independent streams double outstanding loads in this latency-bound loop.
// ---------------------------------------------------------------------------
__global__ __launch_bounds__(256) void aggr_gather(
    const short* __restrict__ msgb, const int* __restrict__ base,
    const int* __restrict__ fill, short* __restrict__ aggrb)
{
    const int node = blockIdx.x * 4 + (threadIdx.x >> 6);
    if (node >= N_NODES) return;
    const int l = threadIdx.x & 63;
    const int b = base[node], e = fill[node];
    const unsigned* mv = (const unsigned*)msgb;
    float a0 = 0.f, a1 = 0.f, b0 = 0.f, b1 = 0.f;
    int i = b;
    for (; i + 1 < e; i += 2) {
        unsigned v0 = __builtin_nontemporal_load(mv + (size_t)i * 64 + l);
        unsigned v1 = __builtin_nontemporal_load(mv + (size_t)(i + 1) * 64 + l);
        a0 += bf2f(v0 & 0xffffu);
        a1 += bf2f(v0 >> 16);
        b0 += bf2f(v1 & 0xffffu);
        b1 += bf2f(v1 >> 16);
    }
    if (i < e) {
        unsigned v = __builtin_nontemporal_load(mv + (size_t)i * 64 + l);
        a0 += bf2f(v & 0xffffu);
        a1 += bf2f(v >> 16);
    }
    a0 += b0; a1 += b1;
    unsigned u = ((unsigned)(unsigned short)f2bf(a1) << 16) |
                 (unsigned)(unsigned short)f2bf(a0);
    ((unsigned*)aggrb)[(size_t)node * 64 + l] = u;
}

// separate coord_pos (r6-validated; fusing into aggr_gather was the r10 regression)
__global__ void coord_pos(const float* __restrict__ pos, const float* __restrict__ cu,
                          const int* __restrict__ base, const int* __restrict__ fill,
                          float* __restrict__ pout)
{
    int n = blockIdx.x * 256 + threadIdx.x;
    if (n < N_NODES) {
        const int b = base[n], e = fill[n];
        float ax = 0.f, ay = 0.f, az = 0.f;
        for (int i = b; i < e; ++i) {
            ax += cu[(size_t)i * 3 + 0];
            ay += cu[(size_t)i * 3 + 1];
            az += cu[(size_t)i * 3 + 2];
        }
        pout[n * 3 + 0] = pos[n * 3 + 0] + ax;
        pout[n * 3 + 1] = pos[n * 3 + 1] + ay;
        pout[n * 3 + 2] = pos[n * 3 + 2] + az;
    }
}

// ---------------------------------------------------------------------------
// Node kernel: h_out = h + mlp([h, aggr]); 2 waves x 32 nodes.
// GATHER=1: stages X directly from bf16 hb + aggrb (no conversion VALU).
// GATHER=0: r6 fp32 staging from h + aggr_msgs (fallback).
// ---------------------------------------------------------------------------
template<int GATHER>
__global__ __launch_bounds__(128, 2) void egnn_node(
    const float* __restrict__ h, const float* __restrict__ aggrf,
    const short* __restrict__ hb, const short* __restrict__ aggrb,
    const float* __restrict__ nb1, const float* __restrict__ nb2,
    const short* __restrict__ wp, float* __restrict__ out)
{
    __shared__ char sm[2][16384];
    const int t = threadIdx.x, w = t >> 6, l = t & 63;
    char* sx = sm[w];
    const bf16x8* wpv = (const bf16x8*)wp;
    const int n0 = blockIdx.x * 64 + w * 32;

    {
        const int n_loc = l & 31, half = l >> 5;
        int gn = n0 + n_loc; if (gn >= N_NODES) gn = N_NODES - 1;
        if (GATHER) {
            const bf16x8* src = (half == 0)
                ? ((const bf16x8*)hb    + (size_t)gn * 16)
                : ((const bf16x8*)aggrb + (size_t)gn * 16);
            #pragma unroll
            for (int c = 0; c < 16; ++c) {
                bf16x8 sv = src[c];
                int byte = n_loc * 512 + (half * 128 + c * 8) * 2;
                byte ^= (n_loc & 7) << 4;
                *(bf16x8*)(sx + byte) = sv;
            }
        } else {
            const float* src = (half == 0) ? (h + (size_t)gn * D)
                                           : (aggrf + (size_t)gn * D);
            #pragma unroll
            for (int c = 0; c < 16; ++c) {
                float4 va = *(const float4*)(src + c * 8);
                float4 vb = *(const float4*)(src + c * 8 + 4);
                float v[8] = {va.x, va.y, va.z, va.w, vb.x, vb.y, vb.z, vb.w};
                bf16x8 sv;
                #pragma unroll
                for (int j = 0; j < 8; ++j) sv[j] = f2bf(v[j]);
                int byte = n_loc * 512 + (half * 128 + c * 8) * 2;
                byte ^= (n_loc & 7) << 4;
                *(bf16x8*)(sx + byte) = sv;
            }
        }
    }
    asm volatile("s_waitcnt lgkmcnt(0)" ::: "memory");

    const int ar = l & 15, ag = l >> 4;
    f32x4 acc0[8], acc1[8];

    #pragma unroll
    for (int n = 0; n < 8; ++n) {
        float b = nb1[n * 16 + ar];
        acc0[n] = splat4(b); acc1[n] = splat4(b);
    }
    GEMM2(8, 512, NW1F)

    #pragma unroll
    for (int m = 0; m < 2; ++m)
        #pragma unroll
        for (int n = 0; n < 8; ++n)
            #pragma unroll
            for (int r = 0; r < 4; ++r) {
                float x = (m == 0) ? acc0[n][r] : acc1[n][r];
                const int rw = m * 16 + ag * 4 + r;
                const int cl = n * 16 + ar;
                int byte = rw * 256 + cl * 2;
                byte ^= (rw & 7) << 4;
                *(short*)(sx + byte) = f2bf(silu_f(x));
            }
    asm volatile("s_waitcnt lgkmcnt(0)" ::: "memory");

    #pragma unroll
    for (int n = 0; n < 8; ++n) {
        float b = nb2[n * 16 + ar];
        acc0[n] = splat4(b); acc1[n] = splat4(b);
    }
    GEMM2(4, 256, NW2F)

    #pragma unroll
    for (int m = 0; m < 2; ++m)
        #pragma unroll
        for (int n = 0; n < 8; ++n)
            #pragma unroll
            for (int r = 0; r < 4; ++r) {
                const int rw = m * 16 + ag * 4 + r;
                const int gnode = n0 + rw;
                if (gnode < N_NODES) {
                    const int cl = n * 16 + ar;
                    float x = (m == 0) ? acc0[n][r] : acc1[n][r];
                    out[(size_t)gnode * D + cl] = h[(size_t)gnode * D + cl] + x;
                }
            }
}

__global__ void egnn_pos(const float* __restrict__ pos,
                         const float* __restrict__ aggr_coord,
                         float* __restrict__ pout)
{
    int i = blockIdx.x * 256 + threadIdx.x;
    if (i < N_NODES * 3) pout[i] = pos[i] + aggr_coord[i];
}

extern "C" void kernel_launch(void* const* d_in, const int* in_sizes, int n_in,
                              void* d_out, int out_size, void* d_ws, size_t ws_size,
                              hipStream_t stream)
{
    const float* h   = (const float*)d_in[0];
    const float* pos = (const float*)d_in[1];
    const int*   ei  = (const int*)d_in[2];
    const float* mw1 = (const float*)d_in[3];
    const float* mb1 = (const float*)d_in[4];
    const float* mw2 = (const float*)d_in[5];
    const float* mb2 = (const float*)d_in[6];
    const float* nw1 = (const float*)d_in[7];
    const float* nb1 = (const float*)d_in[8];
    const float* nw2 = (const float*)d_in[9];
    const float* nb2 = (const float*)d_in[10];
    const float* cw1 = (const float*)d_in[11];
    const float* cb1 = (const float*)d_in[12];
    const float* cw2 = (const float*)d_in[13];
    const float* cb2 = (const float*)d_in[14];

    float* out = (float*)d_out;
    char*  ws  = (char*)d_ws;

    size_t o = 0;
    #define WALLOC(name, bytes) size_t name = o; o = (o + (size_t)(bytes) + 15) & ~(size_t)15;
    WALLOC(o_aggrm, (size_t)N_NODES * D * 4)      // fp32 aggr (fallback) / bf16 aggrb (gather)
    WALLOC(o_aggrc, (size_t)N_NODES * 3 * 4)
    WALLOC(o_wpack, (size_t)TOT_KSTEPS * 8 * 64 * 8 * 2)
    WALLOC(o_hb,    (size_t)N_NODES * D * 2)
    WALLOC(o_cnt,   (size_t)N_NODES * 4)
    WALLOC(o_base,  (size_t)N_NODES * 4)
    WALLOC(o_fill,  (size_t)N_NODES * 4)
    WALLOC(o_bsum,  256 * 4)
    WALLOC(o_boff,  256 * 4)
    WALLOC(o_perm,  (size_t)E_EDGES * 4)
    WALLOC(o_msgb,  (size_t)E_EDGES * D * 2)
    WALLOC(o_cu,    (size_t)E_EDGES * 3 * 4)
    const size_t needed = o;
    #undef WALLOC

    float* aggr_msgs  = (float*)(ws + o_aggrm);
    short* aggrb      = (short*)(ws + o_aggrm);   // bf16 alias (paths disjoint)
    float* aggr_coord = (float*)(ws + o_aggrc);
    short* wpack      = (short*)(ws + o_wpack);
    short* hb         = (short*)(ws + o_hb);
    int*   cnt        = (int*)(ws + o_cnt);
    int*   base       = (int*)(ws + o_base);
    int*   fill       = (int*)(ws + o_fill);
    int*   bsum       = (int*)(ws + o_bsum);
    int*   boff       = (int*)(ws + o_boff);
    int*   perm       = (int*)(ws + o_perm);
    short* msgb       = (short*)(ws + o_msgb);
    float* cu         = (float*)(ws + o_cu);

    const bool gather = (ws_size >= needed);

    hipMemsetAsync(cnt, 0, (size_t)N_NODES * sizeof(int), stream);
    if (!gather)
        hipMemsetAsync(aggr_msgs, 0,
                       (size_t)(N_NODES * D + N_NODES * 3) * sizeof(float), stream);

    pack_w<<<TOT_KSTEPS * 8, 64, 0, stream>>>(mw1, mw2, cw1, nw1, nw2, wpack);
    prep<<<(E_EDGES + 255) / 256, 256, 0, stream>>>(h, ei, hb, cnt);

    scan_blocks<<<SCAN_BLOCKS, 256, 0, stream>>>(cnt, base, bsum);
    scan_bsums<<<1, 256, 0, stream>>>(bsum, boff);
    add_offsets<<<SCAN_BLOCKS, 256, 0, stream>>>(base, boff, fill);
    scatter_edges<<<(E_EDGES + 255) / 256, 256, 0, stream>>>(ei, fill, perm);

    if (gather) {
        egnn_edge<1><<<E_EDGES / 64, 128, 0, stream>>>(
            hb, pos, ei, perm, mb1, mb2, cb1, cw2, cb2, wpack,
            aggr_msgs, aggr_coord, msgb, cu);
        aggr_gather<<<(N_NODES + 3) / 4, 256, 0, stream>>>(msgb, base, fill, aggrb);
        egnn_node<1><<<(N_NODES + 63) / 64, 128, 0, stream>>>(
            h, aggr_msgs, hb, aggrb, nb1, nb2, wpack, out);
        coord_pos<<<(N_NODES + 255) / 256, 256, 0, stream>>>(
            pos, cu, base, fill, out + (size_t)N_NODES * D);
    } else {
        egnn_edge<0><<<E_EDGES / 64, 128, 0, stream>>>(
            hb, pos, ei, perm, mb1, mb2, cb1, cw2, cb2, wpack,
            aggr_msgs, aggr_coord, msgb, cu);
        egnn_node<0><<<(N_NODES + 63) / 64, 128, 0, stream>>>(
            h, aggr_msgs, hb, aggrb, nb1, nb2, wpack, out);
        egnn_pos<<<(N_NODES * 3 + 255) / 256, 256, 0, stream>>>(
            pos, aggr_coord, out + (size_t)N_NODES * D);
    }
}